// Round 2
// 1113.463 us; speedup vs baseline: 1.3030x; 1.3030x over previous
//
#include <hip/hip_runtime.h>
#include <hip/hip_bf16.h>
#include <stdint.h>

// Problem shape (fixed by setup_inputs): x[2,2048,2048] f32, q[32000,2048] i32,
// absmax[32000,8] f32 -> out[2,2048,32000] f32.  GEMM: M=4096,K=2048,N=32000.
#define M_DIM 4096
#define K_DIM 2048
#define N_DIM 32000
#define V_DIM 32000

typedef __attribute__((ext_vector_type(8))) __bf16 bf16x8;
typedef __attribute__((ext_vector_type(4))) float floatx4;

// ---------------------------------------------------------------------------
// async global->LDS 16B/lane copy (wave-uniform LDS base + lane*16)
// ---------------------------------------------------------------------------
__device__ __forceinline__ void async_copy16(const void* g, void* l) {
    __builtin_amdgcn_global_load_lds(
        (const __attribute__((address_space(1))) void*)(uintptr_t)g,
        (__attribute__((address_space(3))) void*)(uint32_t)(uintptr_t)l,
        16, 0, 0);
}

// ---------------------------------------------------------------------------
// Prepass 1: blockwise dequant int32 codes -> bf16 W  (w = (q-127.5)/127.5*am)
// ---------------------------------------------------------------------------
__global__ __launch_bounds__(256) void dequant_w(const int* __restrict__ q,
                                                 const float* __restrict__ absmax,
                                                 __bf16* __restrict__ w) {
    const size_t base = ((size_t)blockIdx.x * 256 + threadIdx.x) * 8;
    const size_t row = base >> 11;            // / K_DIM (2048)
    const int    col = (int)(base & 2047);
    const float  am = absmax[(row << 3) | (col >> 8)];   // 8 qblocks per row
    const float  s  = am * (1.0f / 127.5f);
    const int4* qp = reinterpret_cast<const int4*>(q + base);
    const int4 q0 = qp[0], q1 = qp[1];
    bf16x8 o;
    o[0] = (__bf16)fmaf((float)q0.x, s, -am);
    o[1] = (__bf16)fmaf((float)q0.y, s, -am);
    o[2] = (__bf16)fmaf((float)q0.z, s, -am);
    o[3] = (__bf16)fmaf((float)q0.w, s, -am);
    o[4] = (__bf16)fmaf((float)q1.x, s, -am);
    o[5] = (__bf16)fmaf((float)q1.y, s, -am);
    o[6] = (__bf16)fmaf((float)q1.z, s, -am);
    o[7] = (__bf16)fmaf((float)q1.w, s, -am);
    *reinterpret_cast<bf16x8*>(w + base) = o;
}

// ---------------------------------------------------------------------------
// Prepass 2: x fp32 -> bf16
// ---------------------------------------------------------------------------
__global__ __launch_bounds__(256) void conv_x(const float* __restrict__ x,
                                              __bf16* __restrict__ xb) {
    const size_t base = ((size_t)blockIdx.x * 256 + threadIdx.x) * 8;
    const float4* xp = reinterpret_cast<const float4*>(x + base);
    const float4 a = xp[0], b = xp[1];
    bf16x8 o;
    o[0] = (__bf16)a.x; o[1] = (__bf16)a.y; o[2] = (__bf16)a.z; o[3] = (__bf16)a.w;
    o[4] = (__bf16)b.x; o[5] = (__bf16)b.y; o[6] = (__bf16)b.z; o[7] = (__bf16)b.w;
    *reinterpret_cast<bf16x8*>(xb + base) = o;
}

// ---------------------------------------------------------------------------
// GEMM C[M,N] = A[M,K] * B[N,K]^T
// 256x256 tile, BK=64, 512 thr (8 waves 2Mx4N), 8-phase schedule w/ counted
// vmcnt, 16x32-subtile LDS w/ XOR swizzle (bits 4-5 ^= row bits 1-2),
// setprio around MFMA clusters.  LDS 128 KiB STATIC, 1 block/CU.
// ---------------------------------------------------------------------------
#define PH_BAR() do { asm volatile("" ::: "memory"); \
                      __builtin_amdgcn_s_barrier(); \
                      asm volatile("" ::: "memory"); } while (0)
#define LGKM0()  asm volatile("s_waitcnt lgkmcnt(0)" ::: "memory")
#define VMW(n)   asm volatile("s_waitcnt vmcnt(" #n ")" ::: "memory")
#define PRIO1()  __builtin_amdgcn_s_setprio(1)
#define PRIO0()  __builtin_amdgcn_s_setprio(0)

__global__ __launch_bounds__(512, 2) void gemm_bt(const __bf16* __restrict__ A,
                                                  const __bf16* __restrict__ Bm,
                                                  float* __restrict__ C) {
    // STATIC LDS (128 KiB total) — dynamic extern-shared launch config was the
    // prime suspect in the round-1 container failure; static always launches.
    __shared__ __align__(1024) __bf16 As[32768];   // 64 KiB: [2buf][2half][16 subtiles]
    __shared__ __align__(1024) __bf16 Bs[32768];   // 64 KiB

    const int tid  = threadIdx.x;
    const int w    = tid >> 6;          // wave 0..7
    const int lane = tid & 63;
    const int wr   = w >> 2;            // M half   (0..1)
    const int wc   = w & 3;             // N quarter (0..3)
    const int m16  = lane & 15;
    const int quad = lane >> 4;

    // XCD-aware bijective block swizzle: 2000 blocks = 8 * 250 exactly.
    int flat = (int)(blockIdx.y * 125u + blockIdx.x);
    flat = (flat & 7) * 250 + (flat >> 3);
    const int by = flat / 125;
    const int bx = flat - by * 125;
    const int aRow0 = by << 8;
    const int bCol0 = bx << 8;

    // per-lane swizzled LDS read offset within a 1024B (16x32 bf16) subtile:
    // natural o = row*64 + quad*16 ; swz: o ^= ((row>>1)&3)<<4
    const int laneoff = ((m16 << 6) | (quad << 4)) ^ (((lane >> 1) & 3) << 4);
    const char* aBase = (const char*)As + wr * 16384 + laneoff;
    const char* bBase = (const char*)Bs + (wc >> 1) * 16384 + (wc & 1) * 8192 + laneoff;

#define RDA(b, sub) (*(const bf16x8*)(aBase + (b) * 32768 + (sub) * 1024))
#define RDB(b, sub) (*(const bf16x8*)(bBase + (b) * 32768 + (sub) * 1024))

    // staging: wave w owns row-block w (16 rows) of each 128-row half, cb=0,1.
    // LDS dest is linear (lane*16); SOURCE col is pre-swizzled (inverse = same XOR):
    // lane l -> row l>>2, colseg ((l&3) ^ ((l>>3)&3)) * 8
    const int srow = lane >> 2;
    const int scol = ((lane & 3) ^ ((lane >> 3) & 3)) << 3;
    const __bf16* sA0 = A  + (size_t)(aRow0 +       (w << 4) + srow) * K_DIM + scol;
    const __bf16* sA1 = A  + (size_t)(aRow0 + 128 + (w << 4) + srow) * K_DIM + scol;
    const __bf16* sB0 = Bm + (size_t)(bCol0 +       (w << 4) + srow) * K_DIM + scol;
    const __bf16* sB1 = Bm + (size_t)(bCol0 + 128 + (w << 4) + srow) * K_DIM + scol;
    __bf16* dA = As + (w << 10);        // subtile pair base: (w*2)*512 elems
    __bf16* dB = Bs + (w << 10);

#define STAGE_A(buf, half, kk) do { \
    const __bf16* s_ = ((half) ? sA1 : sA0) + (kk); \
    __bf16* d_ = dA + (buf) * 16384 + (half) * 8192; \
    async_copy16(s_,      d_); \
    async_copy16(s_ + 32, d_ + 512); \
} while (0)
#define STAGE_B(buf, half, kk) do { \
    const __bf16* s_ = ((half) ? sB1 : sB0) + (kk); \
    __bf16* d_ = dB + (buf) * 16384 + (half) * 8192; \
    async_copy16(s_,      d_); \
    async_copy16(s_ + 32, d_ + 512); \
} while (0)

    floatx4 acc[8][4];
#pragma unroll
    for (int i = 0; i < 8; ++i)
#pragma unroll
        for (int j = 0; j < 4; ++j) acc[i][j] = (floatx4)0.0f;

    bf16x8 a0[8], a1[8], bf0, bf1;

#define MF16(aarr, j0, j1) do { \
    _Pragma("unroll") \
    for (int mi_ = 0; mi_ < 8; ++mi_) { \
        acc[mi_][j0] = __builtin_amdgcn_mfma_f32_16x16x32_bf16(aarr[mi_], bf0, acc[mi_][j0], 0, 0, 0); \
        acc[mi_][j1] = __builtin_amdgcn_mfma_f32_16x16x32_bf16(aarr[mi_], bf1, acc[mi_][j1], 0, 0, 0); \
    } \
} while (0)

    // One K-tile = 4 phases.  A-frags front-loaded (p0:ks0, p1:ks1) so the A
    // region is consumed by end of p1 -> safe to prefetch tile t+2's A halves
    // at p2/p3 into the SAME buffer.  B region frees at tile end -> next tile's
    // p0/p1 prefetch tile t+2's B into the other buffer.  vmcnt(4) once per
    // tile (the 4 newest loads = the two A half-tile prefetches still allowed
    // in flight); everything older (incl. next tile's B) is complete.
#define TILE(b, kB, kA, doB, doA, LASTW) do { \
    _Pragma("unroll") \
    for (int i_ = 0; i_ < 8; ++i_) a0[i_] = RDA(b, i_ * 2); \
    bf0 = RDB(b, 0); bf1 = RDB(b, 2); \
    if (doB) STAGE_B(1 - (b), 0, kB); \
    PH_BAR(); LGKM0(); PRIO1(); \
    MF16(a0, 0, 1); \
    PRIO0(); PH_BAR(); \
    _Pragma("unroll") \
    for (int i_ = 0; i_ < 8; ++i_) a1[i_] = RDA(b, i_ * 2 + 1); \
    bf0 = RDB(b, 4); bf1 = RDB(b, 6); \
    if (doB) STAGE_B(1 - (b), 1, kB); \
    PH_BAR(); LGKM0(); PRIO1(); \
    MF16(a0, 2, 3); \
    PRIO0(); PH_BAR(); \
    bf0 = RDB(b, 1); bf1 = RDB(b, 3); \
    if (doA) STAGE_A(b, 0, kA); \
    PH_BAR(); LGKM0(); PRIO1(); \
    MF16(a1, 0, 1); \
    PRIO0(); PH_BAR(); \
    bf0 = RDB(b, 5); bf1 = RDB(b, 7); \
    if (doA) STAGE_A(b, 1, kA); \
    PH_BAR(); LGKM0(); PRIO1(); \
    MF16(a1, 2, 3); \
    PRIO0(); LASTW; PH_BAR(); \
} while (0)

    // prologue: t0 {A0,A1,B0,B1} -> buf0 ; t1 {A0,A1} -> buf1 (12 loads/wave);
    // wait first 8 (t0 complete), t1's A may stay in flight.
    STAGE_A(0, 0, 0);
    STAGE_A(0, 1, 0);
    STAGE_B(0, 0, 0);
    STAGE_B(0, 1, 0);
    STAGE_A(1, 0, 64);
    STAGE_A(1, 1, 64);
    VMW(4);
    PH_BAR();

    // K = 2048 -> 32 K-tiles.  Tiles 0..29 uniform; tile 30 stages only t31's B
    // and drains (vmcnt 0); tile 31 stages nothing.
    int kk = 0;
#pragma unroll 1
    for (int it = 0; it < 15; ++it) {
        TILE(0, kk + 64,  kk + 128, 1, 1, VMW(4));
        TILE(1, kk + 128, kk + 192, 1, 1, VMW(4));
        kk += 128;
    }
    TILE(0, kk + 64, 0, 1, 0, VMW(0));    // tile 30
    TILE(1, 0, 0, 0, 0, (void)0);         // tile 31

    // epilogue: C/D layout col=lane&15, row=quad*4+reg  [verified m89/m91]
    const int colB = bCol0 + (wc << 6) + m16;
#pragma unroll
    for (int mi = 0; mi < 8; ++mi) {
        const size_t rbase = (size_t)(aRow0 + (wr << 7) + mi * 16 + quad * 4) * N_DIM + colB;
#pragma unroll
        for (int ni = 0; ni < 4; ++ni) {
#pragma unroll
            for (int r = 0; r < 4; ++r)
                C[rbase + (size_t)r * N_DIM + ni * 16] = acc[mi][ni][r];
        }
    }
}

// ---------------------------------------------------------------------------
extern "C" void kernel_launch(void* const* d_in, const int* in_sizes, int n_in,
                              void* d_out, int out_size, void* d_ws, size_t ws_size,
                              hipStream_t stream) {
    const float* x  = (const float*)d_in[0];
    const int*   q  = (const int*)d_in[1];
    const float* am = (const float*)d_in[2];
    float* out = (float*)d_out;

    // workspace layout: W bf16 [V,K] then x bf16 [M,K]
    const size_t w_elems = (size_t)V_DIM * K_DIM;          // 65,536,000
    const size_t x_elems = (size_t)M_DIM * K_DIM;          //  8,388,608
    if (ws_size < (w_elems + x_elems) * sizeof(__bf16)) return;  // ~148 MB needed
    __bf16* wb = (__bf16*)d_ws;
    __bf16* xb = wb + w_elems;

    dequant_w<<<(int)(w_elems / 2048), 256, 0, stream>>>(q, am, wb);
    conv_x<<<(int)(x_elems / 2048), 256, 0, stream>>>(x, xb);

    dim3 grid(N_DIM / 256, M_DIM / 256);   // 125 x 16 = 2000 blocks
    gemm_bt<<<grid, 512, 0, stream>>>(xb, wb, out);
}